// Round 1
// baseline (3571.636 us; speedup 1.0000x reference)
//
#include <hip/hip_runtime.h>
#include <hip/hip_bf16.h>
#include <math.h>

#define D_MODEL 256
#define NUM_SLOTS 128
#define RANK 32
#define N_STEPS 6
#define VOCAB 32000
#define SEQ 512
#define BATCH 8
#define NTOK (BATCH*SEQ)
#define LN_EPS 1e-5f
#define SM_SCALE 0.0625f
#define IGROUPS 8
#define IPG (NUM_SLOTS/IGROUPS)

// X[b,l,:] = token_emb[ids[b,l],:] + pos_emb[l,:]
__global__ __launch_bounds__(256) void k_embed(const int* __restrict__ ids,
        const float* __restrict__ tok, const float* __restrict__ pos,
        float* __restrict__ X) {
    int bl = blockIdx.x;
    int d  = threadIdx.x;
    int l  = bl % SEQ;
    int id = ids[bl];
    X[(size_t)bl*D_MODEL + d] = tok[(size_t)id*D_MODEL + d] + pos[l*D_MODEL + d];
}

// C[m,n] = sum_k A[m,k]*B[n,k]   (both row-major, K contiguous)  64x64 tile
__global__ __launch_bounds__(256) void k_gemm_nt(const float* __restrict__ A,
        const float* __restrict__ B, float* __restrict__ C, int M, int N, int K) {
    __shared__ float As[32][64];
    __shared__ float Bs[32][64];
    int bm = blockIdx.x * 64, bn = blockIdx.y * 64;
    int t = threadIdx.x;
    int tm = (t & 15) * 4, tn = (t >> 4) * 4;
    float acc[4][4] = {};
    for (int k0 = 0; k0 < K; k0 += 32) {
        #pragma unroll
        for (int r = 0; r < 8; ++r) {
            int idx = r*256 + t;
            int m = idx >> 5, k = idx & 31;
            As[k][m] = A[(size_t)(bm+m)*K + k0 + k];
        }
        #pragma unroll
        for (int r = 0; r < 8; ++r) {
            int idx = r*256 + t;
            int n = idx >> 5, k = idx & 31;
            Bs[k][n] = B[(size_t)(bn+n)*K + k0 + k];
        }
        __syncthreads();
        #pragma unroll
        for (int k = 0; k < 32; ++k) {
            float4 a4 = *(const float4*)&As[k][tm];
            float4 b4 = *(const float4*)&Bs[k][tn];
            float a[4] = {a4.x,a4.y,a4.z,a4.w};
            float b[4] = {b4.x,b4.y,b4.z,b4.w};
            #pragma unroll
            for (int i = 0; i < 4; ++i)
                #pragma unroll
                for (int jj = 0; jj < 4; ++jj)
                    acc[i][jj] += a[i]*b[jj];
        }
        __syncthreads();
    }
    #pragma unroll
    for (int i = 0; i < 4; ++i) {
        float4 v = make_float4(acc[i][0],acc[i][1],acc[i][2],acc[i][3]);
        *(float4*)&C[(size_t)(bm+tm+i)*N + bn+tn] = v;
    }
}

// 128x128 tile, 8x8 per thread — for the 4096x32000x256 logits GEMM
__global__ __launch_bounds__(256) void k_gemm_nt_big(const float* __restrict__ A,
        const float* __restrict__ B, float* __restrict__ C, int M, int N, int K) {
    __shared__ float As[16][128];
    __shared__ float Bs[16][128];
    int bm = blockIdx.x * 128, bn = blockIdx.y * 128;
    int t = threadIdx.x;
    int tm = (t & 15) * 8, tn = (t >> 4) * 8;
    float acc[8][8] = {};
    for (int k0 = 0; k0 < K; k0 += 16) {
        #pragma unroll
        for (int r = 0; r < 8; ++r) {
            int idx = r*256 + t;
            int m = idx >> 4, k = idx & 15;
            As[k][m] = A[(size_t)(bm+m)*K + k0 + k];
        }
        #pragma unroll
        for (int r = 0; r < 8; ++r) {
            int idx = r*256 + t;
            int n = idx >> 4, k = idx & 15;
            Bs[k][n] = B[(size_t)(bn+n)*K + k0 + k];
        }
        __syncthreads();
        #pragma unroll
        for (int k = 0; k < 16; ++k) {
            float a[8], b[8];
            *(float4*)&a[0] = *(const float4*)&As[k][tm];
            *(float4*)&a[4] = *(const float4*)&As[k][tm+4];
            *(float4*)&b[0] = *(const float4*)&Bs[k][tn];
            *(float4*)&b[4] = *(const float4*)&Bs[k][tn+4];
            #pragma unroll
            for (int i = 0; i < 8; ++i)
                #pragma unroll
                for (int jj = 0; jj < 8; ++jj)
                    acc[i][jj] += a[i]*b[jj];
        }
        __syncthreads();
    }
    #pragma unroll
    for (int i = 0; i < 8; ++i) {
        *(float4*)&C[(size_t)(bm+tm+i)*N + bn+tn]   = make_float4(acc[i][0],acc[i][1],acc[i][2],acc[i][3]);
        *(float4*)&C[(size_t)(bm+tm+i)*N + bn+tn+4] = make_float4(acc[i][4],acc[i][5],acc[i][6],acc[i][7]);
    }
}

// softmax over 128 slots per (b,l) row, then multiply by mask[b,l]
__global__ __launch_bounds__(128) void k_softmax_mask(float* __restrict__ A,
        const int* __restrict__ mask) {
    int row = blockIdx.x;
    int s = threadIdx.x;
    __shared__ float red[128];
    float v = A[(size_t)row*NUM_SLOTS + s] * SM_SCALE;
    red[s] = v; __syncthreads();
    for (int o = 64; o > 0; o >>= 1) { if (s < o) red[s] = fmaxf(red[s], red[s+o]); __syncthreads(); }
    float mx = red[0]; __syncthreads();
    float e = expf(v - mx);
    red[s] = e; __syncthreads();
    for (int o = 64; o > 0; o >>= 1) { if (s < o) red[s] += red[s+o]; __syncthreads(); }
    float sum = red[0];
    float m = (float)mask[row];
    A[(size_t)row*NUM_SLOTS + s] = e / sum * m;
}

// colsum[b,s] = sum_l A[b,l,s] + 1e-8
__global__ __launch_bounds__(128) void k_colsum(const float* __restrict__ A,
        float* __restrict__ cs) {
    int b = blockIdx.x; int s = threadIdx.x;
    const float* Ab = A + (size_t)b*SEQ*NUM_SLOTS + s;
    float acc = 0.f;
    for (int l = 0; l < SEQ; ++l) acc += Ab[(size_t)l*NUM_SLOTS];
    cs[b*NUM_SLOTS + s] = acc + 1e-8f;
}

// H_state[b,s,:] = H[s,:] + (sum_l A[b,l,s]*V[b,l,:]) / colsum[b,s]
__global__ __launch_bounds__(256) void k_ir(const float* __restrict__ A,
        const float* __restrict__ V, const float* __restrict__ H,
        const float* __restrict__ cs, float* __restrict__ Hs) {
    int bs = blockIdx.x; int b = bs >> 7; int s = bs & 127;
    int d = threadIdx.x;
    float inv = 1.0f / cs[bs];
    const float* Ab = A + (size_t)b*SEQ*NUM_SLOTS + s;
    const float* Vb = V + (size_t)b*SEQ*D_MODEL + d;
    float acc = 0.f;
    for (int l = 0; l < SEQ; ++l) acc += Ab[(size_t)l*NUM_SLOTS] * Vb[(size_t)l*D_MODEL];
    Hs[(size_t)bs*D_MODEL + d] = H[s*D_MODEL + d] + acc * inv;
}

// per (j, i-group): partial infl contribution, deterministic (no atomics)
__global__ __launch_bounds__(256) void k_pairs(const float* __restrict__ h,
        const float* __restrict__ Ws, const float* __restrict__ Wt,
        float* __restrict__ part) {
    int j = blockIdx.x;
    int g = blockIdx.y;
    int t = threadIdx.x;
    __shared__ float sh_h[BATCH][D_MODEL];
    __shared__ float sh_inter[BATCH][RANK];
    float acc[BATCH];
    #pragma unroll
    for (int b = 0; b < BATCH; ++b) acc[b] = 0.f;
    int tb = t >> 5, tr = t & 31;
    for (int ii = 0; ii < IPG; ++ii) {
        int i = g*IPG + ii;
        if (i == j) continue;               // block-uniform
        #pragma unroll
        for (int b = 0; b < BATCH; ++b)
            sh_h[b][t] = h[((size_t)b*NUM_SLOTS + i)*D_MODEL + t];
        __syncthreads();
        // inter[tb][tr] = sum_d h[tb,i,d] * Ws[i,j,d,tr]
        const float* ws = Ws + ((size_t)i*NUM_SLOTS + j)*(D_MODEL*RANK);
        float accA = 0.f;
        #pragma unroll 8
        for (int d = 0; d < D_MODEL; ++d)
            accA += sh_h[tb][d] * ws[(size_t)d*RANK + tr];
        sh_inter[tb][tr] = accA;
        __syncthreads();
        // acc[b] += sum_r inter[b][r] * Wt[i,j,r,t]
        const float* wt = Wt + ((size_t)i*NUM_SLOTS + j)*(RANK*D_MODEL);
        #pragma unroll 8
        for (int r = 0; r < RANK; ++r) {
            float w = wt[(size_t)r*D_MODEL + t];
            #pragma unroll
            for (int b = 0; b < BATCH; ++b) acc[b] += sh_inter[b][r] * w;
        }
        __syncthreads();
    }
    #pragma unroll
    for (int b = 0; b < BATCH; ++b)
        part[(((size_t)g*BATCH + b)*NUM_SLOTS + j)*D_MODEL + t] = acc[b];
}

// h[b,j,:] = LN(h[b,j,:] + relu(sum_g part[g,b,j,:])) * gamma + beta
__global__ __launch_bounds__(256) void k_ln(float* __restrict__ h,
        const float* __restrict__ part, const float* __restrict__ gma,
        const float* __restrict__ bta) {
    int bj = blockIdx.x;
    int t = threadIdx.x;
    int b = bj >> 7, j = bj & 127;
    __shared__ float red[256];
    float v = 0.f;
    #pragma unroll
    for (int g = 0; g < IGROUPS; ++g)
        v += part[(((size_t)g*BATCH + b)*NUM_SLOTS + j)*D_MODEL + t];
    float x = h[(size_t)bj*D_MODEL + t] + fmaxf(v, 0.f);
    red[t] = x; __syncthreads();
    for (int o = 128; o > 0; o >>= 1) { if (t < o) red[t] += red[t+o]; __syncthreads(); }
    float mu = red[0] * (1.0f/D_MODEL); __syncthreads();
    float dx = x - mu;
    red[t] = dx*dx; __syncthreads();
    for (int o = 128; o > 0; o >>= 1) { if (t < o) red[t] += red[t+o]; __syncthreads(); }
    float var = red[0] * (1.0f/D_MODEL);
    h[(size_t)bj*D_MODEL + t] = dx * rsqrtf(var + LN_EPS) * gma[t] + bta[t];
}

// A2[b,l,s] = softmax_s( dot(Qout[b,l,:], Kf[b,s,:]) * scale )
__global__ __launch_bounds__(128) void k_attn2(const float* __restrict__ Q,
        const float* __restrict__ Kf, float* __restrict__ A2) {
    int bl = blockIdx.x; int b = bl / SEQ;
    int s = threadIdx.x;
    __shared__ float q[D_MODEL];
    __shared__ float red[128];
    q[s]       = Q[(size_t)bl*D_MODEL + s];
    q[s + 128] = Q[(size_t)bl*D_MODEL + s + 128];
    __syncthreads();
    const float* kf = Kf + ((size_t)b*NUM_SLOTS + s)*D_MODEL;
    float acc = 0.f;
    #pragma unroll 8
    for (int d = 0; d < D_MODEL; ++d) acc += q[d]*kf[d];
    acc *= SM_SCALE;
    red[s] = acc; __syncthreads();
    for (int o = 64; o > 0; o >>= 1) { if (s < o) red[s] = fmaxf(red[s], red[s+o]); __syncthreads(); }
    float mx = red[0]; __syncthreads();
    float e = expf(acc - mx);
    red[s] = e; __syncthreads();
    for (int o = 64; o > 0; o >>= 1) { if (s < o) red[s] += red[s+o]; __syncthreads(); }
    A2[(size_t)bl*NUM_SLOTS + s] = e / red[0];
}

// Y[b,l,:] = sum_s A2[b,l,s] * Vf[b,s,:]
__global__ __launch_bounds__(256) void k_y(const float* __restrict__ A2,
        const float* __restrict__ Vf, float* __restrict__ Y) {
    int bl = blockIdx.x; int b = bl / SEQ;
    int d = threadIdx.x;
    const float* a = A2 + (size_t)bl*NUM_SLOTS;
    const float* v = Vf + (size_t)b*NUM_SLOTS*D_MODEL + d;
    float acc = 0.f;
    #pragma unroll 4
    for (int s = 0; s < NUM_SLOTS; ++s) acc += a[s]*v[(size_t)s*D_MODEL];
    Y[(size_t)bl*D_MODEL + d] = acc;
}

extern "C" void kernel_launch(void* const* d_in, const int* in_sizes, int n_in,
                              void* d_out, int out_size, void* d_ws, size_t ws_size,
                              hipStream_t stream) {
    const int*   ids    = (const int*)d_in[0];
    const int*   amask  = (const int*)d_in[1];
    const float* tok    = (const float*)d_in[2];
    const float* pos    = (const float*)d_in[3];
    const float* Hin    = (const float*)d_in[4];
    const float* Ws     = (const float*)d_in[5];
    const float* Wt     = (const float*)d_in[6];
    const float* Wq_in  = (const float*)d_in[7];
    const float* Wk_sl  = (const float*)d_in[8];
    const float* Wv_in  = (const float*)d_in[9];
    const float* Wq_out = (const float*)d_in[10];
    const float* Wk_fin = (const float*)d_in[11];
    const float* Wv_fin = (const float*)d_in[12];
    const float* Wop    = (const float*)d_in[13];
    const float* lnsc   = (const float*)d_in[14];
    const float* lnbs   = (const float*)d_in[15];
    float* out = (float*)d_out;
    float* ws  = (float*)d_ws;

    float* X    = ws;
    float* Qin  = X    + (size_t)NTOK*D_MODEL;        // 1048576
    float* Vin  = Qin  + (size_t)NTOK*D_MODEL;
    float* Ksl  = Vin  + (size_t)NTOK*D_MODEL;        // 32768
    float* Asc  = Ksl  + (size_t)NUM_SLOTS*D_MODEL;   // 524288
    float* cs   = Asc  + (size_t)NTOK*NUM_SLOTS;      // 1024
    float* Hst  = cs   + (size_t)BATCH*NUM_SLOTS;     // 262144
    float* part = Hst  + (size_t)BATCH*NUM_SLOTS*D_MODEL; // 2097152
    float* Qout = part + (size_t)IGROUPS*BATCH*NUM_SLOTS*D_MODEL;
    float* Kf   = Qout + (size_t)NTOK*D_MODEL;
    float* Vf   = Kf   + (size_t)BATCH*NUM_SLOTS*D_MODEL;
    float* A2   = Vf   + (size_t)BATCH*NUM_SLOTS*D_MODEL;
    float* Yb   = A2   + (size_t)NTOK*NUM_SLOTS;

    // embeddings
    k_embed<<<NTOK, 256, 0, stream>>>(ids, tok, pos, X);
    // compress projections
    k_gemm_nt<<<dim3(NTOK/64, 4), 256, 0, stream>>>(X, Wq_in, Qin, NTOK, D_MODEL, D_MODEL);
    k_gemm_nt<<<dim3(2, 4),       256, 0, stream>>>(Hin, Wk_sl, Ksl, NUM_SLOTS, D_MODEL, D_MODEL);
    k_gemm_nt<<<dim3(NTOK/64, 4), 256, 0, stream>>>(X, Wv_in, Vin, NTOK, D_MODEL, D_MODEL);
    // scores + softmax + mask
    k_gemm_nt<<<dim3(NTOK/64, 2), 256, 0, stream>>>(Qin, Ksl, Asc, NTOK, NUM_SLOTS, D_MODEL);
    k_softmax_mask<<<NTOK, 128, 0, stream>>>(Asc, amask);
    // column-normalize + aggregate into slots
    k_colsum<<<BATCH, 128, 0, stream>>>(Asc, cs);
    k_ir<<<BATCH*NUM_SLOTS, 256, 0, stream>>>(Asc, Vin, Hin, cs, Hst);
    // bilinear slot-interaction steps
    for (int st = 0; st < N_STEPS; ++st) {
        k_pairs<<<dim3(NUM_SLOTS, IGROUPS), 256, 0, stream>>>(Hst, Ws, Wt, part);
        k_ln<<<BATCH*NUM_SLOTS, 256, 0, stream>>>(Hst, part, lnsc + st*D_MODEL, lnbs + st*D_MODEL);
    }
    // expand projections
    k_gemm_nt<<<dim3(NTOK/64, 4), 256, 0, stream>>>(X, Wq_out, Qout, NTOK, D_MODEL, D_MODEL);
    k_gemm_nt<<<dim3(BATCH*NUM_SLOTS/64, 4), 256, 0, stream>>>(Hst, Wk_fin, Kf, BATCH*NUM_SLOTS, D_MODEL, D_MODEL);
    k_gemm_nt<<<dim3(BATCH*NUM_SLOTS/64, 4), 256, 0, stream>>>(Hst, Wv_fin, Vf, BATCH*NUM_SLOTS, D_MODEL, D_MODEL);
    // expand attention
    k_attn2<<<NTOK, 128, 0, stream>>>(Qout, Kf, A2);
    k_y<<<NTOK, 256, 0, stream>>>(A2, Vf, Yb);
    // logits
    k_gemm_nt_big<<<dim3(NTOK/128, VOCAB/128), 256, 0, stream>>>(Yb, Wop, out, NTOK, VOCAB, D_MODEL);
}

// Round 2
// 2769.507 us; speedup vs baseline: 1.2896x; 1.2896x over previous
//
#include <hip/hip_runtime.h>
#include <hip/hip_bf16.h>
#include <math.h>

#define D_MODEL 256
#define NUM_SLOTS 128
#define RANK 32
#define N_STEPS 6
#define VOCAB 32000
#define SEQ 512
#define BATCH 8
#define NTOK (BATCH*SEQ)
#define LN_EPS 1e-5f
#define SM_SCALE 0.0625f
#define IGROUPS 8
#define IPG (NUM_SLOTS/IGROUPS)

typedef __attribute__((ext_vector_type(8))) short bf16x8;
typedef __attribute__((ext_vector_type(4))) float f32x4;

__device__ inline unsigned short f2bf(float x) {
    unsigned u = __float_as_uint(x);
    unsigned r = u + 0x7fff + ((u >> 16) & 1);
    return (unsigned short)(r >> 16);
}
__device__ inline float bf2f(unsigned short h) {
    return __uint_as_float(((unsigned)h) << 16);
}

// X[b,l,:] = token_emb[ids[b,l],:] + pos_emb[l,:]
__global__ __launch_bounds__(256) void k_embed(const int* __restrict__ ids,
        const float* __restrict__ tok, const float* __restrict__ pos,
        float* __restrict__ X) {
    int bl = blockIdx.x;
    int d  = threadIdx.x;
    int l  = bl % SEQ;
    int id = ids[bl];
    X[(size_t)bl*D_MODEL + d] = tok[(size_t)id*D_MODEL + d] + pos[l*D_MODEL + d];
}

// C[m,n] = sum_k A[m,k]*B[n,k]   (both row-major, K contiguous)  64x64 tile
__global__ __launch_bounds__(256) void k_gemm_nt(const float* __restrict__ A,
        const float* __restrict__ B, float* __restrict__ C, int M, int N, int K) {
    __shared__ float As[32][64];
    __shared__ float Bs[32][64];
    int bm = blockIdx.x * 64, bn = blockIdx.y * 64;
    int t = threadIdx.x;
    int tm = (t & 15) * 4, tn = (t >> 4) * 4;
    float acc[4][4] = {};
    for (int k0 = 0; k0 < K; k0 += 32) {
        #pragma unroll
        for (int r = 0; r < 8; ++r) {
            int idx = r*256 + t;
            int m = idx >> 5, k = idx & 31;
            As[k][m] = A[(size_t)(bm+m)*K + k0 + k];
        }
        #pragma unroll
        for (int r = 0; r < 8; ++r) {
            int idx = r*256 + t;
            int n = idx >> 5, k = idx & 31;
            Bs[k][n] = B[(size_t)(bn+n)*K + k0 + k];
        }
        __syncthreads();
        #pragma unroll
        for (int k = 0; k < 32; ++k) {
            float4 a4 = *(const float4*)&As[k][tm];
            float4 b4 = *(const float4*)&Bs[k][tn];
            float a[4] = {a4.x,a4.y,a4.z,a4.w};
            float b[4] = {b4.x,b4.y,b4.z,b4.w};
            #pragma unroll
            for (int i = 0; i < 4; ++i)
                #pragma unroll
                for (int jj = 0; jj < 4; ++jj)
                    acc[i][jj] += a[i]*b[jj];
        }
        __syncthreads();
    }
    #pragma unroll
    for (int i = 0; i < 4; ++i) {
        float4 v = make_float4(acc[i][0],acc[i][1],acc[i][2],acc[i][3]);
        *(float4*)&C[(size_t)(bm+tm+i)*N + bn+tn] = v;
    }
}

// split fp32 -> bf16 hi + bf16 lo (exactly representable residual split)
__global__ __launch_bounds__(256) void k_split(const float* __restrict__ in,
        unsigned short* __restrict__ hi, unsigned short* __restrict__ lo, int n4) {
    int i = blockIdx.x*256 + threadIdx.x;
    if (i >= n4) return;
    float4 v = ((const float4*)in)[i];
    float f[4] = {v.x, v.y, v.z, v.w};
    ushort4 h, lw;
    unsigned short* hp = &h.x; unsigned short* lp = &lw.x;
    #pragma unroll
    for (int j = 0; j < 4; ++j) {
        unsigned short hb = f2bf(f[j]);
        hp[j] = hb;
        lp[j] = f2bf(f[j] - bf2f(hb));
    }
    ((ushort4*)hi)[i] = h;
    ((ushort4*)lo)[i] = lw;
}

// logits GEMM: C[m,n] = sum_k Y[m,k]*W[n,k] via 3-pass split-bf16 MFMA.
// A (Y): [NTOK][256] hi/lo bf16, B (W): [VOCAB][256] hi/lo bf16, C fp32.
__global__ __launch_bounds__(256) void k_logits(
        const unsigned short* __restrict__ Ahg, const unsigned short* __restrict__ Alg,
        const unsigned short* __restrict__ Bhg, const unsigned short* __restrict__ Blg,
        float* __restrict__ C) {
    __shared__ short lds[4*128*64];
    short* Ah = lds;
    short* Al = lds + 8192;
    short* Bh = lds + 16384;
    short* Bl = lds + 24576;
    int bm = blockIdx.x * 128, bn = blockIdx.y * 128;
    int t = threadIdx.x;
    int w = t >> 6, l = t & 63;
    int wr = w >> 1, wc = w & 1;          // 2x2 waves, each 64x64 out
    int lr = l & 15, lk = l >> 4;         // fragment row / k-group
    f32x4 acc[4][4];
    #pragma unroll
    for (int mi = 0; mi < 4; ++mi)
        #pragma unroll
        for (int ni = 0; ni < 4; ++ni)
            acc[mi][ni] = (f32x4){0.f,0.f,0.f,0.f};

    for (int kc = 0; kc < 4; ++kc) {
        // stage 128x64 bf16 tiles (hi+lo for A and B), XOR-swizzled 16B slots
        #pragma unroll
        for (int i = 0; i < 4; ++i) {
            int v = t + i*256;
            int row = v >> 3, cv = v & 7;
            int so = row*64 + ((cv ^ (row & 7)) << 3);
            size_t ga = (size_t)(bm+row)*256 + kc*64 + cv*8;
            size_t gb = (size_t)(bn+row)*256 + kc*64 + cv*8;
            *(bf16x8*)&Ah[so] = *(const bf16x8*)&Ahg[ga];
            *(bf16x8*)&Al[so] = *(const bf16x8*)&Alg[ga];
            *(bf16x8*)&Bh[so] = *(const bf16x8*)&Bhg[gb];
            *(bf16x8*)&Bl[so] = *(const bf16x8*)&Blg[gb];
        }
        __syncthreads();
        #pragma unroll
        for (int s = 0; s < 2; ++s) {
            bf16x8 ah[4], al[4], bh[4], bl[4];
            #pragma unroll
            for (int mi = 0; mi < 4; ++mi) {
                int row = wr*64 + mi*16 + lr;
                int off = row*64 + ((((s<<2)+lk) ^ (row&7)) << 3);
                ah[mi] = *(bf16x8*)&Ah[off];
                al[mi] = *(bf16x8*)&Al[off];
            }
            #pragma unroll
            for (int ni = 0; ni < 4; ++ni) {
                int row = wc*64 + ni*16 + lr;
                int off = row*64 + ((((s<<2)+lk) ^ (row&7)) << 3);
                bh[ni] = *(bf16x8*)&Bh[off];
                bl[ni] = *(bf16x8*)&Bl[off];
            }
            #pragma unroll
            for (int mi = 0; mi < 4; ++mi)
                #pragma unroll
                for (int ni = 0; ni < 4; ++ni) {
                    acc[mi][ni] = __builtin_amdgcn_mfma_f32_16x16x32_bf16(ah[mi], bh[ni], acc[mi][ni], 0, 0, 0);
                    acc[mi][ni] = __builtin_amdgcn_mfma_f32_16x16x32_bf16(ah[mi], bl[ni], acc[mi][ni], 0, 0, 0);
                    acc[mi][ni] = __builtin_amdgcn_mfma_f32_16x16x32_bf16(al[mi], bh[ni], acc[mi][ni], 0, 0, 0);
                }
        }
        __syncthreads();
    }
    // epilogue: C[row][col], row=(lane>>4)*4+reg (A dim), col=lane&15 (B dim)
    #pragma unroll
    for (int mi = 0; mi < 4; ++mi)
        #pragma unroll
        for (int ni = 0; ni < 4; ++ni) {
            int col = bn + wc*64 + ni*16 + lr;
            #pragma unroll
            for (int r = 0; r < 4; ++r) {
                int row = bm + wr*64 + mi*16 + lk*4 + r;
                C[(size_t)row*VOCAB + col] = acc[mi][ni][r];
            }
        }
}

// softmax over 128 slots per (b,l) row, then multiply by mask[b,l]
__global__ __launch_bounds__(128) void k_softmax_mask(float* __restrict__ A,
        const int* __restrict__ mask) {
    int row = blockIdx.x;
    int s = threadIdx.x;
    __shared__ float red[128];
    float v = A[(size_t)row*NUM_SLOTS + s] * SM_SCALE;
    red[s] = v; __syncthreads();
    for (int o = 64; o > 0; o >>= 1) { if (s < o) red[s] = fmaxf(red[s], red[s+o]); __syncthreads(); }
    float mx = red[0]; __syncthreads();
    float e = expf(v - mx);
    red[s] = e; __syncthreads();
    for (int o = 64; o > 0; o >>= 1) { if (s < o) red[s] += red[s+o]; __syncthreads(); }
    float sum = red[0];
    float m = (float)mask[row];
    A[(size_t)row*NUM_SLOTS + s] = e / sum * m;
}

// colsum[b,s] = sum_l A[b,l,s] + 1e-8
__global__ __launch_bounds__(128) void k_colsum(const float* __restrict__ A,
        float* __restrict__ cs) {
    int b = blockIdx.x; int s = threadIdx.x;
    const float* Ab = A + (size_t)b*SEQ*NUM_SLOTS + s;
    float acc = 0.f;
    for (int l = 0; l < SEQ; ++l) acc += Ab[(size_t)l*NUM_SLOTS];
    cs[b*NUM_SLOTS + s] = acc + 1e-8f;
}

// H_state[b,s,:] = H[s,:] + (sum_l A[b,l,s]*V[b,l,:]) / colsum[b,s]
__global__ __launch_bounds__(256) void k_ir(const float* __restrict__ A,
        const float* __restrict__ V, const float* __restrict__ H,
        const float* __restrict__ cs, float* __restrict__ Hs) {
    int bs = blockIdx.x; int b = bs >> 7; int s = bs & 127;
    int d = threadIdx.x;
    float inv = 1.0f / cs[bs];
    const float* Ab = A + (size_t)b*SEQ*NUM_SLOTS + s;
    const float* Vb = V + (size_t)b*SEQ*D_MODEL + d;
    float acc = 0.f;
    for (int l = 0; l < SEQ; ++l) acc += Ab[(size_t)l*NUM_SLOTS] * Vb[(size_t)l*D_MODEL];
    Hs[(size_t)bs*D_MODEL + d] = H[s*D_MODEL + d] + acc * inv;
}

// per (j, i-group): partial infl contribution, deterministic (no atomics)
__global__ __launch_bounds__(256) void k_pairs(const float* __restrict__ h,
        const float* __restrict__ Ws, const float* __restrict__ Wt,
        float* __restrict__ part) {
    int j = blockIdx.x;
    int g = blockIdx.y;
    int t = threadIdx.x;
    __shared__ float sh_h[BATCH][D_MODEL];
    __shared__ float sh_inter[BATCH][RANK];
    float acc[BATCH];
    #pragma unroll
    for (int b = 0; b < BATCH; ++b) acc[b] = 0.f;
    int tb = t >> 5, tr = t & 31;
    for (int ii = 0; ii < IPG; ++ii) {
        int i = g*IPG + ii;
        if (i == j) continue;               // block-uniform
        #pragma unroll
        for (int b = 0; b < BATCH; ++b)
            sh_h[b][t] = h[((size_t)b*NUM_SLOTS + i)*D_MODEL + t];
        __syncthreads();
        // inter[tb][tr] = sum_d h[tb,i,d] * Ws[i,j,d,tr]
        const float* ws = Ws + ((size_t)i*NUM_SLOTS + j)*(D_MODEL*RANK);
        float accA = 0.f;
        #pragma unroll 8
        for (int d = 0; d < D_MODEL; ++d)
            accA += sh_h[tb][d] * ws[(size_t)d*RANK + tr];
        sh_inter[tb][tr] = accA;
        __syncthreads();
        // acc[b] += sum_r inter[b][r] * Wt[i,j,r,t]
        const float* wt = Wt + ((size_t)i*NUM_SLOTS + j)*(RANK*D_MODEL);
        #pragma unroll 8
        for (int r = 0; r < RANK; ++r) {
            float w = wt[(size_t)r*D_MODEL + t];
            #pragma unroll
            for (int b = 0; b < BATCH; ++b) acc[b] += sh_inter[b][r] * w;
        }
        __syncthreads();
    }
    #pragma unroll
    for (int b = 0; b < BATCH; ++b)
        part[(((size_t)g*BATCH + b)*NUM_SLOTS + j)*D_MODEL + t] = acc[b];
}

// h[b,j,:] = LN(h[b,j,:] + relu(sum_g part[g,b,j,:])) * gamma + beta
__global__ __launch_bounds__(256) void k_ln(float* __restrict__ h,
        const float* __restrict__ part, const float* __restrict__ gma,
        const float* __restrict__ bta) {
    int bj = blockIdx.x;
    int t = threadIdx.x;
    int b = bj >> 7, j = bj & 127;
    __shared__ float red[256];
    float v = 0.f;
    #pragma unroll
    for (int g = 0; g < IGROUPS; ++g)
        v += part[(((size_t)g*BATCH + b)*NUM_SLOTS + j)*D_MODEL + t];
    float x = h[(size_t)bj*D_MODEL + t] + fmaxf(v, 0.f);
    red[t] = x; __syncthreads();
    for (int o = 128; o > 0; o >>= 1) { if (t < o) red[t] += red[t+o]; __syncthreads(); }
    float mu = red[0] * (1.0f/D_MODEL); __syncthreads();
    float dx = x - mu;
    red[t] = dx*dx; __syncthreads();
    for (int o = 128; o > 0; o >>= 1) { if (t < o) red[t] += red[t+o]; __syncthreads(); }
    float var = red[0] * (1.0f/D_MODEL);
    h[(size_t)bj*D_MODEL + t] = dx * rsqrtf(var + LN_EPS) * gma[t] + bta[t];
}

// A2[b,l,s] = softmax_s( dot(Qout[b,l,:], Kf[b,s,:]) * scale )
__global__ __launch_bounds__(128) void k_attn2(const float* __restrict__ Q,
        const float* __restrict__ Kf, float* __restrict__ A2) {
    int bl = blockIdx.x; int b = bl / SEQ;
    int s = threadIdx.x;
    __shared__ float q[D_MODEL];
    __shared__ float red[128];
    q[s]       = Q[(size_t)bl*D_MODEL + s];
    q[s + 128] = Q[(size_t)bl*D_MODEL + s + 128];
    __syncthreads();
    const float* kf = Kf + ((size_t)b*NUM_SLOTS + s)*D_MODEL;
    float acc = 0.f;
    #pragma unroll 8
    for (int d = 0; d < D_MODEL; ++d) acc += q[d]*kf[d];
    acc *= SM_SCALE;
    red[s] = acc; __syncthreads();
    for (int o = 64; o > 0; o >>= 1) { if (s < o) red[s] = fmaxf(red[s], red[s+o]); __syncthreads(); }
    float mx = red[0]; __syncthreads();
    float e = expf(acc - mx);
    red[s] = e; __syncthreads();
    for (int o = 64; o > 0; o >>= 1) { if (s < o) red[s] += red[s+o]; __syncthreads(); }
    A2[(size_t)bl*NUM_SLOTS + s] = e / red[0];
}

// Y[b,l,:] = sum_s A2[b,l,s] * Vf[b,s,:]
__global__ __launch_bounds__(256) void k_y(const float* __restrict__ A2,
        const float* __restrict__ Vf, float* __restrict__ Y) {
    int bl = blockIdx.x; int b = bl / SEQ;
    int d = threadIdx.x;
    const float* a = A2 + (size_t)bl*NUM_SLOTS;
    const float* v = Vf + (size_t)b*NUM_SLOTS*D_MODEL + d;
    float acc = 0.f;
    #pragma unroll 4
    for (int s = 0; s < NUM_SLOTS; ++s) acc += a[s]*v[(size_t)s*D_MODEL];
    Y[(size_t)bl*D_MODEL + d] = acc;
}

extern "C" void kernel_launch(void* const* d_in, const int* in_sizes, int n_in,
                              void* d_out, int out_size, void* d_ws, size_t ws_size,
                              hipStream_t stream) {
    const int*   ids    = (const int*)d_in[0];
    const int*   amask  = (const int*)d_in[1];
    const float* tok    = (const float*)d_in[2];
    const float* pos    = (const float*)d_in[3];
    const float* Hin    = (const float*)d_in[4];
    const float* Ws     = (const float*)d_in[5];
    const float* Wt     = (const float*)d_in[6];
    const float* Wq_in  = (const float*)d_in[7];
    const float* Wk_sl  = (const float*)d_in[8];
    const float* Wv_in  = (const float*)d_in[9];
    const float* Wq_out = (const float*)d_in[10];
    const float* Wk_fin = (const float*)d_in[11];
    const float* Wv_fin = (const float*)d_in[12];
    const float* Wop    = (const float*)d_in[13];
    const float* lnsc   = (const float*)d_in[14];
    const float* lnbs   = (const float*)d_in[15];
    float* out = (float*)d_out;
    float* ws  = (float*)d_ws;

    float* X    = ws;
    float* Qin  = X    + (size_t)NTOK*D_MODEL;
    float* Vin  = Qin  + (size_t)NTOK*D_MODEL;
    float* Ksl  = Vin  + (size_t)NTOK*D_MODEL;
    float* Asc  = Ksl  + (size_t)NUM_SLOTS*D_MODEL;
    float* cs   = Asc  + (size_t)NTOK*NUM_SLOTS;
    float* Hst  = cs   + (size_t)BATCH*NUM_SLOTS;
    float* part = Hst  + (size_t)BATCH*NUM_SLOTS*D_MODEL;
    float* Qout = part + (size_t)IGROUPS*BATCH*NUM_SLOTS*D_MODEL;
    float* Kf   = Qout + (size_t)NTOK*D_MODEL;
    float* Vf   = Kf   + (size_t)BATCH*NUM_SLOTS*D_MODEL;
    float* A2   = Vf   + (size_t)BATCH*NUM_SLOTS*D_MODEL;
    float* Yb   = A2   + (size_t)NTOK*NUM_SLOTS;
    // bf16 split buffers appended after fp32 scratch
    unsigned short* Yh = (unsigned short*)(Yb + (size_t)NTOK*D_MODEL);
    unsigned short* Yl = Yh + (size_t)NTOK*D_MODEL;
    unsigned short* Wh = Yl + (size_t)NTOK*D_MODEL;
    unsigned short* Wl = Wh + (size_t)VOCAB*D_MODEL;

    // one-time weight split for logits GEMM (independent -> launch first)
    k_split<<<(VOCAB*D_MODEL/4 + 255)/256, 256, 0, stream>>>(Wop, Wh, Wl, VOCAB*D_MODEL/4);

    // embeddings
    k_embed<<<NTOK, 256, 0, stream>>>(ids, tok, pos, X);
    // compress projections
    k_gemm_nt<<<dim3(NTOK/64, 4), 256, 0, stream>>>(X, Wq_in, Qin, NTOK, D_MODEL, D_MODEL);
    k_gemm_nt<<<dim3(2, 4),       256, 0, stream>>>(Hin, Wk_sl, Ksl, NUM_SLOTS, D_MODEL, D_MODEL);
    k_gemm_nt<<<dim3(NTOK/64, 4), 256, 0, stream>>>(X, Wv_in, Vin, NTOK, D_MODEL, D_MODEL);
    // scores + softmax + mask
    k_gemm_nt<<<dim3(NTOK/64, 2), 256, 0, stream>>>(Qin, Ksl, Asc, NTOK, NUM_SLOTS, D_MODEL);
    k_softmax_mask<<<NTOK, 128, 0, stream>>>(Asc, amask);
    // column-normalize + aggregate into slots
    k_colsum<<<BATCH, 128, 0, stream>>>(Asc, cs);
    k_ir<<<BATCH*NUM_SLOTS, 256, 0, stream>>>(Asc, Vin, Hin, cs, Hst);
    // bilinear slot-interaction steps
    for (int st = 0; st < N_STEPS; ++st) {
        k_pairs<<<dim3(NUM_SLOTS, IGROUPS), 256, 0, stream>>>(Hst, Ws, Wt, part);
        k_ln<<<BATCH*NUM_SLOTS, 256, 0, stream>>>(Hst, part, lnsc + st*D_MODEL, lnbs + st*D_MODEL);
    }
    // expand projections
    k_gemm_nt<<<dim3(NTOK/64, 4), 256, 0, stream>>>(X, Wq_out, Qout, NTOK, D_MODEL, D_MODEL);
    k_gemm_nt<<<dim3(BATCH*NUM_SLOTS/64, 4), 256, 0, stream>>>(Hst, Wk_fin, Kf, BATCH*NUM_SLOTS, D_MODEL, D_MODEL);
    k_gemm_nt<<<dim3(BATCH*NUM_SLOTS/64, 4), 256, 0, stream>>>(Hst, Wv_fin, Vf, BATCH*NUM_SLOTS, D_MODEL, D_MODEL);
    // expand attention
    k_attn2<<<NTOK, 128, 0, stream>>>(Qout, Kf, A2);
    k_y<<<NTOK, 256, 0, stream>>>(A2, Vf, Yb);
    // logits: split Y, then 3-pass split-bf16 MFMA GEMM
    k_split<<<(NTOK*D_MODEL/4 + 255)/256, 256, 0, stream>>>(Yb, Yh, Yl, NTOK*D_MODEL/4);
    k_logits<<<dim3(NTOK/128, VOCAB/128), 256, 0, stream>>>(Yh, Yl, Wh, Wl, out);
}

// Round 4
// 1788.031 us; speedup vs baseline: 1.9975x; 1.5489x over previous
//
#include <hip/hip_runtime.h>
#include <hip/hip_bf16.h>
#include <math.h>

#define D_MODEL 256
#define NUM_SLOTS 128
#define RANK 32
#define N_STEPS 6
#define VOCAB 32000
#define SEQ 512
#define BATCH 8
#define NTOK (BATCH*SEQ)
#define LN_EPS 1e-5f
#define SM_SCALE 0.0625f
#define IGROUPS 8
#define IPG (NUM_SLOTS/IGROUPS)

typedef __attribute__((ext_vector_type(8))) short bf16x8;
typedef __attribute__((ext_vector_type(8))) _Float16 f16x8;
typedef __attribute__((ext_vector_type(4))) float f32x4;

#define GLD_LDS16(g, l) __builtin_amdgcn_global_load_lds( \
    (const __attribute__((address_space(1))) unsigned int*)(g), \
    (__attribute__((address_space(3))) unsigned int*)(l), 16, 0, 0)

__device__ inline unsigned short f2bf(float x) {
    unsigned u = __float_as_uint(x);
    unsigned r = u + 0x7fff + ((u >> 16) & 1);
    return (unsigned short)(r >> 16);
}
__device__ inline float bf2f(unsigned short h) {
    return __uint_as_float(((unsigned)h) << 16);
}
__device__ inline unsigned pk2(float a, float b) {
    auto v = __builtin_amdgcn_cvt_pkrtz(a, b);
    union { decltype(v) x; unsigned u; } c;
    c.x = v;
    return c.u;
}

// X[b,l,:] = token_emb[ids[b,l],:] + pos_emb[l,:]
__global__ __launch_bounds__(256) void k_embed(const int* __restrict__ ids,
        const float* __restrict__ tok, const float* __restrict__ pos,
        float* __restrict__ X) {
    int bl = blockIdx.x;
    int d  = threadIdx.x;
    int l  = bl % SEQ;
    int id = ids[bl];
    X[(size_t)bl*D_MODEL + d] = tok[(size_t)id*D_MODEL + d] + pos[l*D_MODEL + d];
}

// C[m,n] = sum_k A[m,k]*B[n,k]   (both row-major, K contiguous)  64x64 tile
__global__ __launch_bounds__(256) void k_gemm_nt(const float* __restrict__ A,
        const float* __restrict__ B, float* __restrict__ C, int M, int N, int K) {
    __shared__ float As[32][64];
    __shared__ float Bs[32][64];
    int bm = blockIdx.x * 64, bn = blockIdx.y * 64;
    int t = threadIdx.x;
    int tm = (t & 15) * 4, tn = (t >> 4) * 4;
    float acc[4][4] = {};
    for (int k0 = 0; k0 < K; k0 += 32) {
        #pragma unroll
        for (int r = 0; r < 8; ++r) {
            int idx = r*256 + t;
            int m = idx >> 5, k = idx & 31;
            As[k][m] = A[(size_t)(bm+m)*K + k0 + k];
        }
        #pragma unroll
        for (int r = 0; r < 8; ++r) {
            int idx = r*256 + t;
            int n = idx >> 5, k = idx & 31;
            Bs[k][n] = B[(size_t)(bn+n)*K + k0 + k];
        }
        __syncthreads();
        #pragma unroll
        for (int k = 0; k < 32; ++k) {
            float4 a4 = *(const float4*)&As[k][tm];
            float4 b4 = *(const float4*)&Bs[k][tn];
            float a[4] = {a4.x,a4.y,a4.z,a4.w};
            float b[4] = {b4.x,b4.y,b4.z,b4.w};
            #pragma unroll
            for (int i = 0; i < 4; ++i)
                #pragma unroll
                for (int jj = 0; jj < 4; ++jj)
                    acc[i][jj] += a[i]*b[jj];
        }
        __syncthreads();
    }
    #pragma unroll
    for (int i = 0; i < 4; ++i) {
        float4 v = make_float4(acc[i][0],acc[i][1],acc[i][2],acc[i][3]);
        *(float4*)&C[(size_t)(bm+tm+i)*N + bn+tn] = v;
    }
}

// split fp32 -> bf16 hi + bf16 lo
__global__ __launch_bounds__(256) void k_split(const float* __restrict__ in,
        unsigned short* __restrict__ hi, unsigned short* __restrict__ lo, int n4) {
    int i = blockIdx.x*256 + threadIdx.x;
    if (i >= n4) return;
    float4 v = ((const float4*)in)[i];
    float f[4] = {v.x, v.y, v.z, v.w};
    ushort4 h, lw;
    unsigned short* hp = &h.x; unsigned short* lp = &lw.x;
    #pragma unroll
    for (int j = 0; j < 4; ++j) {
        unsigned short hb = f2bf(f[j]);
        hp[j] = hb;
        lp[j] = f2bf(f[j] - bf2f(hb));
    }
    ((ushort4*)hi)[i] = h;
    ((ushort4*)lo)[i] = lw;
}

// logits GEMM: 3-pass split-bf16 MFMA
__global__ __launch_bounds__(256) void k_logits(
        const unsigned short* __restrict__ Ahg, const unsigned short* __restrict__ Alg,
        const unsigned short* __restrict__ Bhg, const unsigned short* __restrict__ Blg,
        float* __restrict__ C) {
    __shared__ short lds[4*128*64];
    short* Ah = lds;
    short* Al = lds + 8192;
    short* Bh = lds + 16384;
    short* Bl = lds + 24576;
    int bm = blockIdx.x * 128, bn = blockIdx.y * 128;
    int t = threadIdx.x;
    int w = t >> 6, l = t & 63;
    int wr = w >> 1, wc = w & 1;
    int lr = l & 15, lk = l >> 4;
    f32x4 acc[4][4];
    #pragma unroll
    for (int mi = 0; mi < 4; ++mi)
        #pragma unroll
        for (int ni = 0; ni < 4; ++ni)
            acc[mi][ni] = (f32x4){0.f,0.f,0.f,0.f};

    for (int kc = 0; kc < 4; ++kc) {
        #pragma unroll
        for (int i = 0; i < 4; ++i) {
            int v = t + i*256;
            int row = v >> 3, cv = v & 7;
            int so = row*64 + ((cv ^ (row & 7)) << 3);
            size_t ga = (size_t)(bm+row)*256 + kc*64 + cv*8;
            size_t gb = (size_t)(bn+row)*256 + kc*64 + cv*8;
            *(bf16x8*)&Ah[so] = *(const bf16x8*)&Ahg[ga];
            *(bf16x8*)&Al[so] = *(const bf16x8*)&Alg[ga];
            *(bf16x8*)&Bh[so] = *(const bf16x8*)&Bhg[gb];
            *(bf16x8*)&Bl[so] = *(const bf16x8*)&Blg[gb];
        }
        __syncthreads();
        #pragma unroll
        for (int s = 0; s < 2; ++s) {
            bf16x8 ah[4], al[4], bh[4], bl[4];
            #pragma unroll
            for (int mi = 0; mi < 4; ++mi) {
                int row = wr*64 + mi*16 + lr;
                int off = row*64 + ((((s<<2)+lk) ^ (row&7)) << 3);
                ah[mi] = *(bf16x8*)&Ah[off];
                al[mi] = *(bf16x8*)&Al[off];
            }
            #pragma unroll
            for (int ni = 0; ni < 4; ++ni) {
                int row = wc*64 + ni*16 + lr;
                int off = row*64 + ((((s<<2)+lk) ^ (row&7)) << 3);
                bh[ni] = *(bf16x8*)&Bh[off];
                bl[ni] = *(bf16x8*)&Bl[off];
            }
            #pragma unroll
            for (int mi = 0; mi < 4; ++mi)
                #pragma unroll
                for (int ni = 0; ni < 4; ++ni) {
                    acc[mi][ni] = __builtin_amdgcn_mfma_f32_16x16x32_bf16(ah[mi], bh[ni], acc[mi][ni], 0, 0, 0);
                    acc[mi][ni] = __builtin_amdgcn_mfma_f32_16x16x32_bf16(ah[mi], bl[ni], acc[mi][ni], 0, 0, 0);
                    acc[mi][ni] = __builtin_amdgcn_mfma_f32_16x16x32_bf16(al[mi], bh[ni], acc[mi][ni], 0, 0, 0);
                }
        }
        __syncthreads();
    }
    #pragma unroll
    for (int mi = 0; mi < 4; ++mi)
        #pragma unroll
        for (int ni = 0; ni < 4; ++ni) {
            int col = bn + wc*64 + ni*16 + lr;
            #pragma unroll
            for (int r = 0; r < 4; ++r) {
                int row = bm + wr*64 + mi*16 + lk*4 + r;
                C[(size_t)row*VOCAB + col] = acc[mi][ni][r];
            }
        }
}

__global__ __launch_bounds__(128) void k_softmax_mask(float* __restrict__ A,
        const int* __restrict__ mask) {
    int row = blockIdx.x;
    int s = threadIdx.x;
    __shared__ float red[128];
    float v = A[(size_t)row*NUM_SLOTS + s] * SM_SCALE;
    red[s] = v; __syncthreads();
    for (int o = 64; o > 0; o >>= 1) { if (s < o) red[s] = fmaxf(red[s], red[s+o]); __syncthreads(); }
    float mx = red[0]; __syncthreads();
    float e = expf(v - mx);
    red[s] = e; __syncthreads();
    for (int o = 64; o > 0; o >>= 1) { if (s < o) red[s] += red[s+o]; __syncthreads(); }
    float sum = red[0];
    float m = (float)mask[row];
    A[(size_t)row*NUM_SLOTS + s] = e / sum * m;
}

__global__ __launch_bounds__(128) void k_colsum(const float* __restrict__ A,
        float* __restrict__ cs) {
    int b = blockIdx.x; int s = threadIdx.x;
    const float* Ab = A + (size_t)b*SEQ*NUM_SLOTS + s;
    float acc = 0.f;
    for (int l = 0; l < SEQ; ++l) acc += Ab[(size_t)l*NUM_SLOTS];
    cs[b*NUM_SLOTS + s] = acc + 1e-8f;
}

__global__ __launch_bounds__(256) void k_ir(const float* __restrict__ A,
        const float* __restrict__ V, const float* __restrict__ H,
        const float* __restrict__ cs, float* __restrict__ Hs) {
    int bs = blockIdx.x; int b = bs >> 7; int s = bs & 127;
    int d = threadIdx.x;
    float inv = 1.0f / cs[bs];
    const float* Ab = A + (size_t)b*SEQ*NUM_SLOTS + s;
    const float* Vb = V + (size_t)b*SEQ*D_MODEL + d;
    float acc = 0.f;
    for (int l = 0; l < SEQ; ++l) acc += Ab[(size_t)l*NUM_SLOTS] * Vb[(size_t)l*D_MODEL];
    Hs[(size_t)bs*D_MODEL + d] = H[s*D_MODEL + d] + acc * inv;
}

// ---- one-time fp32->fp16 weight conversion into MFMA fragment order ----
// WF layout per pair p=(j*128+i): [0:8192) ushorts = Ws frags (A-op of pass1),
// chunk ((ks*2+mt)*64+l): e -> Ws[i,j][d=ks*32+(l>>4)*8+e][r=mt*16+(l&15)]
// [8192:16384) = Wt frags (B-op of pass2),
// chunk (nt*64+l): e -> Wt[i,j][r=(l>>4)*8+e][d=nt*16+(l&15)]
__global__ __launch_bounds__(256) void k_convert(const float* __restrict__ Ws,
        const float* __restrict__ Wt, unsigned short* __restrict__ WF) {
    int i = blockIdx.x, j = blockIdx.y;
    int t = threadIdx.x;
    __shared__ float lds[256*36];
    size_t sBase = ((size_t)i*128 + j)*8192;
    size_t pOut = ((size_t)j*128 + i)*16384;
    // --- Ws: stage [256][32] -> lds [d][r] pad 36 ---
    const float4* s4 = (const float4*)(Ws + sBase);
    #pragma unroll
    for (int e4 = 0; e4 < 8; ++e4) {
        float4 v = s4[e4*256 + t];
        int d = e4*32 + (t>>3), r = 4*(t&7);
        *(float4*)&lds[d*36 + r] = v;
    }
    __syncthreads();
    bool diag = (i == j);
    #pragma unroll
    for (int c4 = 0; c4 < 4; ++c4) {
        int chunk = c4*256 + t;
        int ks = chunk >> 7, mt = (chunk >> 6) & 1, l = chunk & 63;
        int g = l >> 4, c = l & 15;
        union { f16x8 v; } o;
        #pragma unroll
        for (int e = 0; e < 8; ++e) {
            float f = diag ? 0.f : lds[(ks*32 + g*8 + e)*36 + mt*16 + c];
            o.v[e] = (_Float16)f;
        }
        *(f16x8*)(WF + pOut + (size_t)chunk*8) = o.v;
    }
    __syncthreads();
    // --- Wt: stage [32][256] -> lds [r][d] pad 260 ---
    const float4* s4b = (const float4*)(Wt + sBase);
    #pragma unroll
    for (int e4 = 0; e4 < 8; ++e4) {
        float4 v = s4b[e4*256 + t];
        int r = e4*4 + (t>>6), d = 4*(t&63);
        *(float4*)&lds[r*260 + d] = v;
    }
    __syncthreads();
    #pragma unroll
    for (int c4 = 0; c4 < 4; ++c4) {
        int chunk = c4*256 + t;
        int nt = chunk >> 6, l = chunk & 63;
        int g = l >> 4, c = l & 15;
        union { f16x8 v; } o;
        #pragma unroll
        for (int e = 0; e < 8; ++e)
            o.v[e] = (_Float16)lds[(g*8 + e)*260 + nt*16 + c];
        *(f16x8*)(WF + pOut + 8192 + (size_t)chunk*8) = o.v;
    }
}

// ---- MFMA slot-pair kernel: block (j, g) accumulates 16 i's ----
__global__ __launch_bounds__(256) void k_pairs_mfma(const float* __restrict__ h,
        const unsigned short* __restrict__ WF, float* __restrict__ part) {
    __shared__ unsigned short lds[32768];   // 2 x 32KB double buffer
    int j = blockIdx.x, g = blockIdx.y;
    int t = threadIdx.x, w = t >> 6, l = t & 63;
    int lg = l >> 4, c = l & 15;
    const unsigned short* base = WF + ((size_t)j*128 + g*16)*16384;
    // prologue: stage ii=0 into buf 0 (each wave its 8KB quarter)
    #pragma unroll
    for (int q = 0; q < 8; ++q) {
        int uoff = w*4096 + q*512;
        GLD_LDS16(base + uoff + l*8, &lds[uoff]);
    }
    f32x4 acc[4];
    #pragma unroll
    for (int nt = 0; nt < 4; ++nt) acc[nt] = (f32x4){0.f,0.f,0.f,0.f};

    #pragma unroll 2
    for (int ii = 0; ii < 16; ++ii) {
        int cur = ii & 1;
        __syncthreads();    // stage(cur) drained; all waves done with prev buf
        if (ii < 15) {
            const unsigned short* src = base + (size_t)(ii+1)*16384;
            unsigned short* dst = &lds[(cur^1)*16384];
            #pragma unroll
            for (int q = 0; q < 8; ++q) {
                int uoff = w*4096 + q*512;
                GLD_LDS16(src + uoff + l*8, dst + uoff);
            }
        }
        // h B-frags (direct from global, fp32->fp16, zero pad rows b>=8)
        f16x8 hb[8];
        if (c < 8) {
            const float* hrow = h + ((size_t)c*NUM_SLOTS + (g*16+ii))*D_MODEL + lg*8;
            #pragma unroll
            for (int ks = 0; ks < 8; ++ks) {
                float4 v0 = *(const float4*)(hrow + ks*32);
                float4 v1 = *(const float4*)(hrow + ks*32 + 4);
                float f[8] = {v0.x,v0.y,v0.z,v0.w,v1.x,v1.y,v1.z,v1.w};
                #pragma unroll
                for (int e = 0; e < 8; ++e) hb[ks][e] = (_Float16)f[e];
            }
        } else {
            #pragma unroll
            for (int ks = 0; ks < 8; ++ks)
                #pragma unroll
                for (int e = 0; e < 8; ++e) hb[ks][e] = (_Float16)0.f;
        }
        // pass1: interT[r=0..31][b] = sum_d WsT[r][d] h[b][d]
        f32x4 d1[2];
        d1[0] = (f32x4){0.f,0.f,0.f,0.f};
        d1[1] = (f32x4){0.f,0.f,0.f,0.f};
        const unsigned short* buf = &lds[cur*16384];
        #pragma unroll
        for (int ks = 0; ks < 8; ++ks) {
            f16x8 a0 = *(const f16x8*)(buf + (ks*2+0)*512 + l*8);
            f16x8 a1 = *(const f16x8*)(buf + (ks*2+1)*512 + l*8);
            d1[0] = __builtin_amdgcn_mfma_f32_16x16x32_f16(a0, hb[ks], d1[0], 0, 0, 0);
            d1[1] = __builtin_amdgcn_mfma_f32_16x16x32_f16(a1, hb[ks], d1[1], 0, 0, 0);
        }
        // pack interT to fp16 pairs, shuffle into pass2 A-frag:
        // lane (g=lg,c) needs inter[b=c][r=8*lg+e]; source lane 16*(2(lg&1)+(e>=4))+c,
        // mtile lg>>1, pair word (e>>1)&1
        unsigned q0 = pk2(d1[0][0], d1[0][1]);
        unsigned q1 = pk2(d1[0][2], d1[0][3]);
        unsigned s0 = pk2(d1[1][0], d1[1][1]);
        unsigned s1 = pk2(d1[1][2], d1[1][3]);
        int srcLo = 32*(lg & 1) + c;
        int srcHi = srcLo + 16;
        unsigned a0 = (unsigned)__shfl((int)q0, srcLo, 64);
        unsigned a1 = (unsigned)__shfl((int)q1, srcLo, 64);
        unsigned a2 = (unsigned)__shfl((int)q0, srcHi, 64);
        unsigned a3 = (unsigned)__shfl((int)q1, srcHi, 64);
        unsigned b0 = (unsigned)__shfl((int)s0, srcLo, 64);
        unsigned b1 = (unsigned)__shfl((int)s1, srcLo, 64);
        unsigned b2 = (unsigned)__shfl((int)s0, srcHi, 64);
        unsigned b3 = (unsigned)__shfl((int)s1, srcHi, 64);
        bool himt = ((lg >> 1) & 1);
        union { unsigned u[4]; f16x8 v; } A2u;
        A2u.u[0] = himt ? b0 : a0;
        A2u.u[1] = himt ? b1 : a1;
        A2u.u[2] = himt ? b2 : a2;
        A2u.u[3] = himt ? b3 : a3;
        // pass2: out[b][d] += sum_r inter[b][r] Wt[r][d]; wave w owns d-tiles w*4..w*4+3
        #pragma unroll
        for (int nt = 0; nt < 4; ++nt) {
            f16x8 bfr = *(const f16x8*)(buf + 8192 + (size_t)((w*4+nt)*64 + l)*8);
            acc[nt] = __builtin_amdgcn_mfma_f32_16x16x32_f16(A2u.v, bfr, acc[nt], 0, 0, 0);
        }
    }
    // store: lanes lg<2 hold rows b = lg*4+reg (0..7)
    if (lg < 2) {
        #pragma unroll
        for (int nt = 0; nt < 4; ++nt) {
            int d = (w*4 + nt)*16 + c;
            #pragma unroll
            for (int r = 0; r < 4; ++r) {
                int b = lg*4 + r;
                part[(((size_t)g*BATCH + b)*NUM_SLOTS + j)*D_MODEL + d] = acc[nt][r];
            }
        }
    }
}

// fallback fp32 pairs kernel (used when ws too small for WF)
__global__ __launch_bounds__(256) void k_pairs(const float* __restrict__ h,
        const float* __restrict__ Ws, const float* __restrict__ Wt,
        float* __restrict__ part) {
    int j = blockIdx.x;
    int g = blockIdx.y;
    int t = threadIdx.x;
    __shared__ float sh_h[BATCH][D_MODEL];
    __shared__ float sh_inter[BATCH][RANK];
    float acc[BATCH];
    #pragma unroll
    for (int b = 0; b < BATCH; ++b) acc[b] = 0.f;
    int tb = t >> 5, tr = t & 31;
    for (int ii = 0; ii < IPG; ++ii) {
        int i = g*IPG + ii;
        if (i == j) continue;
        #pragma unroll
        for (int b = 0; b < BATCH; ++b)
            sh_h[b][t] = h[((size_t)b*NUM_SLOTS + i)*D_MODEL + t];
        __syncthreads();
        const float* ws = Ws + ((size_t)i*NUM_SLOTS + j)*(D_MODEL*RANK);
        float accA = 0.f;
        #pragma unroll 8
        for (int d = 0; d < D_MODEL; ++d)
            accA += sh_h[tb][d] * ws[(size_t)d*RANK + tr];
        sh_inter[tb][tr] = accA;
        __syncthreads();
        const float* wt = Wt + ((size_t)i*NUM_SLOTS + j)*(RANK*D_MODEL);
        #pragma unroll 8
        for (int r = 0; r < RANK; ++r) {
            float w = wt[(size_t)r*D_MODEL + t];
            #pragma unroll
            for (int b = 0; b < BATCH; ++b) acc[b] += sh_inter[b][r] * w;
        }
        __syncthreads();
    }
    #pragma unroll
    for (int b = 0; b < BATCH; ++b)
        part[(((size_t)g*BATCH + b)*NUM_SLOTS + j)*D_MODEL + t] = acc[b];
}

__global__ __launch_bounds__(256) void k_ln(float* __restrict__ h,
        const float* __restrict__ part, const float* __restrict__ gma,
        const float* __restrict__ bta) {
    int bj = blockIdx.x;
    int t = threadIdx.x;
    int b = bj >> 7, j = bj & 127;
    __shared__ float red[256];
    float v = 0.f;
    #pragma unroll
    for (int g = 0; g < IGROUPS; ++g)
        v += part[(((size_t)g*BATCH + b)*NUM_SLOTS + j)*D_MODEL + t];
    float x = h[(size_t)bj*D_MODEL + t] + fmaxf(v, 0.f);
    red[t] = x; __syncthreads();
    for (int o = 128; o > 0; o >>= 1) { if (t < o) red[t] += red[t+o]; __syncthreads(); }
    float mu = red[0] * (1.0f/D_MODEL); __syncthreads();
    float dx = x - mu;
    red[t] = dx*dx; __syncthreads();
    for (int o = 128; o > 0; o >>= 1) { if (t < o) red[t] += red[t+o]; __syncthreads(); }
    float var = red[0] * (1.0f/D_MODEL);
    h[(size_t)bj*D_MODEL + t] = dx * rsqrtf(var + LN_EPS) * gma[t] + bta[t];
}

__global__ __launch_bounds__(128) void k_attn2(const float* __restrict__ Q,
        const float* __restrict__ Kf, float* __restrict__ A2) {
    int bl = blockIdx.x; int b = bl / SEQ;
    int s = threadIdx.x;
    __shared__ float q[D_MODEL];
    __shared__ float red[128];
    q[s]       = Q[(size_t)bl*D_MODEL + s];
    q[s + 128] = Q[(size_t)bl*D_MODEL + s + 128];
    __syncthreads();
    const float* kf = Kf + ((size_t)b*NUM_SLOTS + s)*D_MODEL;
    float acc = 0.f;
    #pragma unroll 8
    for (int d = 0; d < D_MODEL; ++d) acc += q[d]*kf[d];
    acc *= SM_SCALE;
    red[s] = acc; __syncthreads();
    for (int o = 64; o > 0; o >>= 1) { if (s < o) red[s] = fmaxf(red[s], red[s+o]); __syncthreads(); }
    float mx = red[0]; __syncthreads();
    float e = expf(acc - mx);
    red[s] = e; __syncthreads();
    for (int o = 64; o > 0; o >>= 1) { if (s < o) red[s] += red[s+o]; __syncthreads(); }
    A2[(size_t)bl*NUM_SLOTS + s] = e / red[0];
}

__global__ __launch_bounds__(256) void k_y(const float* __restrict__ A2,
        const float* __restrict__ Vf, float* __restrict__ Y) {
    int bl = blockIdx.x; int b = bl / SEQ;
    int d = threadIdx.x;
    const float* a = A2 + (size_t)bl*NUM_SLOTS;
    const float* v = Vf + (size_t)b*NUM_SLOTS*D_MODEL + d;
    float acc = 0.f;
    #pragma unroll 4
    for (int s = 0; s < NUM_SLOTS; ++s) acc += a[s]*v[(size_t)s*D_MODEL];
    Y[(size_t)bl*D_MODEL + d] = acc;
}

extern "C" void kernel_launch(void* const* d_in, const int* in_sizes, int n_in,
                              void* d_out, int out_size, void* d_ws, size_t ws_size,
                              hipStream_t stream) {
    const int*   ids    = (const int*)d_in[0];
    const int*   amask  = (const int*)d_in[1];
    const float* tok    = (const float*)d_in[2];
    const float* pos    = (const float*)d_in[3];
    const float* Hin    = (const float*)d_in[4];
    const float* Ws     = (const float*)d_in[5];
    const float* Wt     = (const float*)d_in[6];
    const float* Wq_in  = (const float*)d_in[7];
    const float* Wk_sl  = (const float*)d_in[8];
    const float* Wv_in  = (const float*)d_in[9];
    const float* Wq_out = (const float*)d_in[10];
    const float* Wk_fin = (const float*)d_in[11];
    const float* Wv_fin = (const float*)d_in[12];
    const float* Wop    = (const float*)d_in[13];
    const float* lnsc   = (const float*)d_in[14];
    const float* lnbs   = (const float*)d_in[15];
    float* out = (float*)d_out;

    const size_t WF_USH = (size_t)16384 * 16384;     // 512 MiB of ushorts
    const size_t F32_FLOATS = 18449408ULL;           // fp32 scratch region
    const bool useF16 = ws_size >= WF_USH*2 + F32_FLOATS*4 + 256;

    unsigned short* WF = (unsigned short*)d_ws;
    float* ws = useF16 ? (float*)(WF + WF_USH) : (float*)d_ws;

    float* X    = ws;
    float* Qin  = X    + (size_t)NTOK*D_MODEL;
    float* Vin  = Qin  + (size_t)NTOK*D_MODEL;
    float* Ksl  = Vin  + (size_t)NTOK*D_MODEL;
    float* Asc  = Ksl  + (size_t)NUM_SLOTS*D_MODEL;
    float* cs   = Asc  + (size_t)NTOK*NUM_SLOTS;
    float* Hst  = cs   + (size_t)BATCH*NUM_SLOTS;
    float* part = Hst  + (size_t)BATCH*NUM_SLOTS*D_MODEL;
    float* Qout = part + (size_t)IGROUPS*BATCH*NUM_SLOTS*D_MODEL;
    float* Kf   = Qout + (size_t)NTOK*D_MODEL;
    float* Vf   = Kf   + (size_t)BATCH*NUM_SLOTS*D_MODEL;
    float* A2   = Vf   + (size_t)BATCH*NUM_SLOTS*D_MODEL;
    float* Yb   = A2   + (size_t)NTOK*NUM_SLOTS;
    unsigned short* Yh = (unsigned short*)(Yb + (size_t)NTOK*D_MODEL);
    unsigned short* Yl = Yh + (size_t)NTOK*D_MODEL;
    unsigned short* Wh = Yl + (size_t)NTOK*D_MODEL;
    unsigned short* Wl = Wh + (size_t)VOCAB*D_MODEL;

    // one-time weight conversions (independent of the rest)
    if (useF16)
        k_convert<<<dim3(128, 128), 256, 0, stream>>>(Ws, Wt, WF);
    k_split<<<(VOCAB*D_MODEL/4 + 255)/256, 256, 0, stream>>>(Wop, Wh, Wl, VOCAB*D_MODEL/4);

    // embeddings
    k_embed<<<NTOK, 256, 0, stream>>>(ids, tok, pos, X);
    // compress projections
    k_gemm_nt<<<dim3(NTOK/64, 4), 256, 0, stream>>>(X, Wq_in, Qin, NTOK, D_MODEL, D_MODEL);
    k_gemm_nt<<<dim3(2, 4),       256, 0, stream>>>(Hin, Wk_sl, Ksl, NUM_SLOTS, D_MODEL, D_MODEL);
    k_gemm_nt<<<dim3(NTOK/64, 4), 256, 0, stream>>>(X, Wv_in, Vin, NTOK, D_MODEL, D_MODEL);
    // scores + softmax + mask
    k_gemm_nt<<<dim3(NTOK/64, 2), 256, 0, stream>>>(Qin, Ksl, Asc, NTOK, NUM_SLOTS, D_MODEL);
    k_softmax_mask<<<NTOK, 128, 0, stream>>>(Asc, amask);
    // column-normalize + aggregate into slots
    k_colsum<<<BATCH, 128, 0, stream>>>(Asc, cs);
    k_ir<<<BATCH*NUM_SLOTS, 256, 0, stream>>>(Asc, Vin, Hin, cs, Hst);
    // bilinear slot-interaction steps
    for (int st = 0; st < N_STEPS; ++st) {
        if (useF16)
            k_pairs_mfma<<<dim3(NUM_SLOTS, IGROUPS), 256, 0, stream>>>(Hst, WF, part);
        else
            k_pairs<<<dim3(NUM_SLOTS, IGROUPS), 256, 0, stream>>>(Hst, Ws, Wt, part);
        k_ln<<<BATCH*NUM_SLOTS, 256, 0, stream>>>(Hst, part, lnsc + st*D_MODEL, lnbs + st*D_MODEL);
    }
    // expand projections
    k_gemm_nt<<<dim3(NTOK/64, 4), 256, 0, stream>>>(X, Wq_out, Qout, NTOK, D_MODEL, D_MODEL);
    k_gemm_nt<<<dim3(BATCH*NUM_SLOTS/64, 4), 256, 0, stream>>>(Hst, Wk_fin, Kf, BATCH*NUM_SLOTS, D_MODEL, D_MODEL);
    k_gemm_nt<<<dim3(BATCH*NUM_SLOTS/64, 4), 256, 0, stream>>>(Hst, Wv_fin, Vf, BATCH*NUM_SLOTS, D_MODEL, D_MODEL);
    // expand attention
    k_attn2<<<NTOK, 128, 0, stream>>>(Qout, Kf, A2);
    k_y<<<NTOK, 256, 0, stream>>>(A2, Vf, Yb);
    // logits
    k_split<<<(NTOK*D_MODEL/4 + 255)/256, 256, 0, stream>>>(Yb, Yh, Yl, NTOK*D_MODEL/4);
    k_logits<<<dim3(NTOK/128, VOCAB/128), 256, 0, stream>>>(Yh, Yl, Wh, Wl, out);
}